// Round 5
// baseline (25.279 us; speedup 1.0000x reference)
//
#include <hip/hip_runtime.h>

// Problem constants (from setup_inputs): B=32, P=512, D=384, max_len=2048.
#define LR_B      32
#define LR_P      512
#define LR_D      384
#define LR_MAXLEN 2048
#define LR_V4     (LR_D / 4)        // 96 float4 per row
#define LR_FPB    64                // frames per block
#define LR_THREADS 512
#define LR_F4PB   (LR_FPB * LR_V4)  // 6144 float4 per block
#define LR_F4PT   (LR_F4PB / LR_THREADS)  // 12 float4 per thread

#define LR_CHUNKS  (LR_MAXLEN / LR_FPB)        // 32 chunks per batch
#define LR_GBLOCKS (LR_B * LR_CHUNKS)          // 1024 blocks
#define LR_NXCD    8
#define LR_CPX     (LR_GBLOCKS / LR_NXCD)      // 128 blocks per XCD

// Native clang vector type — required by __builtin_nontemporal_store.
typedef float f32x4 __attribute__((ext_vector_type(4)));

// ---------------------------------------------------------------------------
// Fully fused kernel. Each block owns 64 consecutive frames of one batch:
//   1. load the batch's 512 durations (1 per thread),
//   2. wave-shuffle inclusive scan (1 barrier before scatter),
//   3. scatter each thread's phoneme interval into the 64-entry window,
//   4. branchless 3-phase gather: 12 LDS idx reads -> 12 unconditional
//      global loads (row clamped to 0 for masked frames, so the compiler
//      can issue all loads back-to-back: full memory-level parallelism) ->
//      12 select + nontemporal stores.
// XCD-chunk swizzle: each XCD owns 4 consecutive batches (3.1 MB < 4 MB L2).
// ---------------------------------------------------------------------------
__global__ __launch_bounds__(LR_THREADS) void lr_fused(
    const int*   __restrict__ dur,     // [B][P]
    const f32x4* __restrict__ x4,      // [B][P][V4]
    f32x4*       __restrict__ out4,    // [B][MAXLEN][V4]
    float*       __restrict__ mel_out) // [B], float-encoded
{
    // Bijective chunked XCD swizzle (1024 % 8 == 0).
    const int bid = blockIdx.x;
    const int lb  = (bid & (LR_NXCD - 1)) * LR_CPX + (bid >> 3);

    const int b    = lb >> 5;           // lb / 32 : batch
    const int c    = lb & 31;           // chunk within batch
    const int base = c * LR_FPB;        // first frame of this block's window

    const int tid  = threadIdx.x;
    const int lane = tid & 63;
    const int wid  = tid >> 6;          // 8 waves

    __shared__ int smem_idx[LR_FPB];    // frame -> phoneme (-1 = masked)
    __shared__ int wsum[LR_THREADS / 64];

    if (tid < LR_FPB) smem_idx[tid] = -1;

    // Each thread owns phoneme `tid`.
    const int e = dur[b * LR_P + tid];
    int s = e;

    // Inclusive wave scan (6 shuffle steps, no barriers).
    #pragma unroll
    for (int off = 1; off < 64; off <<= 1) {
        int u = __shfl_up(s, off, 64);
        if (lane >= off) s += u;
    }
    if (lane == 63) wsum[wid] = s;
    __syncthreads();   // covers smem_idx init + wsum

    int woff = 0, total = 0;
    #pragma unroll
    for (int i = 0; i < LR_THREADS / 64; ++i) {
        int w = wsum[i];
        woff  += (i < wid) ? w : 0;
        total += w;
    }
    const int end   = s + woff;         // exclusive end of phoneme tid's span
    const int start = end - e;          // start of phoneme tid's span

    // Scatter this thread's interval into the block window (dur <= 4).
    {
        const int lo = max(start, base), hi = min(end, base + LR_FPB);
        for (int f = lo; f < hi; ++f) smem_idx[f - base] = tid;
    }
    if (c == 0 && tid == 0) mel_out[b] = (float)total;  // mel_len as float
    __syncthreads();

    // ---- 3-phase branchless gather --------------------------------------
    const f32x4* xb = x4 + (size_t)b * LR_P * LR_V4;
    f32x4*       ob = out4 + ((size_t)b * LR_MAXLEN + base) * LR_V4;

    int      pr[LR_F4PT];
    unsigned vv[LR_F4PT];
    #pragma unroll
    for (int k = 0; k < LR_F4PT; ++k) {
        const unsigned j     = tid + k * LR_THREADS;   // [0, 6144)
        const unsigned frame = j / LR_V4;              // magic-mul
        vv[k] = j - frame * LR_V4;
        pr[k] = smem_idx[frame];                       // broadcast read
    }

    f32x4 vals[LR_F4PT];
    #pragma unroll
    for (int k = 0; k < LR_F4PT; ++k) {
        const unsigned row = (unsigned)max(pr[k], 0);  // clamp: load row 0 if masked
        vals[k] = xb[row * LR_V4 + vv[k]];             // unconditional -> hoistable
    }

    const f32x4 zero = (f32x4){0.f, 0.f, 0.f, 0.f};
    #pragma unroll
    for (int k = 0; k < LR_F4PT; ++k) {
        f32x4 v = (pr[k] < 0) ? zero : vals[k];        // cndmask
        __builtin_nontemporal_store(v, &ob[tid + k * LR_THREADS]);
    }
}

extern "C" void kernel_launch(void* const* d_in, const int* in_sizes, int n_in,
                              void* d_out, int out_size, void* d_ws, size_t ws_size,
                              hipStream_t stream)
{
    const float* x   = (const float*)d_in[0];  // [B][P][D] float32
    const int*   dur = (const int*)d_in[1];    // [B][P] int32
    // d_in[2] = max_len scalar (2048), compile-time constant here.

    float* out = (float*)d_out;                          // [B][MAXLEN][D]
    float* mel = out + (size_t)LR_B * LR_MAXLEN * LR_D;  // [B] float-encoded

    lr_fused<<<LR_GBLOCKS, LR_THREADS, 0, stream>>>(
        dur, (const f32x4*)x, (f32x4*)out, mel);
}

// Round 6
// 23.398 us; speedup vs baseline: 1.0804x; 1.0804x over previous
//
#include <hip/hip_runtime.h>

// Problem constants (from setup_inputs): B=32, P=512, D=384, max_len=2048.
#define LR_B      32
#define LR_P      512
#define LR_D      384
#define LR_MAXLEN 2048
#define LR_V4     (LR_D / 4)        // 96 float4 per row
#define LR_FPB    64                // frames per block
#define LR_THREADS 512
#define LR_F4PB   (LR_FPB * LR_V4)  // 6144 float4 per block
#define LR_F4PT   (LR_F4PB / LR_THREADS)  // 12 float4 per thread

#define LR_CHUNKS  (LR_MAXLEN / LR_FPB)        // 32 chunks per batch
#define LR_GBLOCKS (LR_B * LR_CHUNKS)          // 1024 blocks
#define LR_NXCD    8
#define LR_CPX     (LR_GBLOCKS / LR_NXCD)      // 128 blocks per XCD

typedef float f32x4 __attribute__((ext_vector_type(4)));

// ---------------------------------------------------------------------------
// Fully fused kernel. Each block owns 64 consecutive frames of one batch:
//   1. load the batch's 512 durations (1 per thread),
//   2. wave-shuffle inclusive scan (1 barrier before scatter),
//   3. scatter each thread's phoneme interval into the 64-entry window,
//   4. branchless 3-phase gather, REGULAR stores (A/B vs round-4 NT stores:
//      fillBufferAligned sustains 6.8 TB/s with regular write-back stores;
//      nt bypasses L2 allocation and may de-rate the store pipe).
// XCD-chunk swizzle: each XCD owns 4 consecutive batches (3.1 MB < 4 MB L2).
// ---------------------------------------------------------------------------
__global__ __launch_bounds__(LR_THREADS) void lr_fused(
    const int*   __restrict__ dur,     // [B][P]
    const f32x4* __restrict__ x4,      // [B][P][V4]
    f32x4*       __restrict__ out4,    // [B][MAXLEN][V4]
    float*       __restrict__ mel_out) // [B], float-encoded
{
    // Bijective chunked XCD swizzle (1024 % 8 == 0).
    const int bid = blockIdx.x;
    const int lb  = (bid & (LR_NXCD - 1)) * LR_CPX + (bid >> 3);

    const int b    = lb >> 5;           // lb / 32 : batch
    const int c    = lb & 31;           // chunk within batch
    const int base = c * LR_FPB;        // first frame of this block's window

    const int tid  = threadIdx.x;
    const int lane = tid & 63;
    const int wid  = tid >> 6;          // 8 waves

    __shared__ int smem_idx[LR_FPB];    // frame -> phoneme (-1 = masked)
    __shared__ int wsum[LR_THREADS / 64];

    if (tid < LR_FPB) smem_idx[tid] = -1;

    // Each thread owns phoneme `tid`.
    const int e = dur[b * LR_P + tid];
    int s = e;

    // Inclusive wave scan (6 shuffle steps, no barriers).
    #pragma unroll
    for (int off = 1; off < 64; off <<= 1) {
        int u = __shfl_up(s, off, 64);
        if (lane >= off) s += u;
    }
    if (lane == 63) wsum[wid] = s;
    __syncthreads();   // covers smem_idx init + wsum

    int woff = 0, total = 0;
    #pragma unroll
    for (int i = 0; i < LR_THREADS / 64; ++i) {
        int w = wsum[i];
        woff  += (i < wid) ? w : 0;
        total += w;
    }
    const int end   = s + woff;         // exclusive end of phoneme tid's span
    const int start = end - e;          // start of phoneme tid's span

    // Scatter this thread's interval into the block window (dur <= 4).
    {
        const int lo = max(start, base), hi = min(end, base + LR_FPB);
        for (int f = lo; f < hi; ++f) smem_idx[f - base] = tid;
    }
    if (c == 0 && tid == 0) mel_out[b] = (float)total;  // mel_len as float
    __syncthreads();

    // ---- 3-phase branchless gather --------------------------------------
    const f32x4* xb = x4 + (size_t)b * LR_P * LR_V4;
    f32x4*       ob = out4 + ((size_t)b * LR_MAXLEN + base) * LR_V4;

    int      pr[LR_F4PT];
    unsigned vv[LR_F4PT];
    #pragma unroll
    for (int k = 0; k < LR_F4PT; ++k) {
        const unsigned j     = tid + k * LR_THREADS;   // [0, 6144)
        const unsigned frame = j / LR_V4;              // magic-mul
        vv[k] = j - frame * LR_V4;
        pr[k] = smem_idx[frame];                       // broadcast read
    }

    f32x4 vals[LR_F4PT];
    #pragma unroll
    for (int k = 0; k < LR_F4PT; ++k) {
        const unsigned row = (unsigned)max(pr[k], 0);  // clamp: load row 0 if masked
        vals[k] = xb[row * LR_V4 + vv[k]];             // unconditional -> hoistable
    }

    const f32x4 zero = (f32x4){0.f, 0.f, 0.f, 0.f};
    #pragma unroll
    for (int k = 0; k < LR_F4PT; ++k) {
        f32x4 v = (pr[k] < 0) ? zero : vals[k];        // cndmask
        ob[tid + k * LR_THREADS] = v;                  // regular store (A/B vs nt)
    }
}

extern "C" void kernel_launch(void* const* d_in, const int* in_sizes, int n_in,
                              void* d_out, int out_size, void* d_ws, size_t ws_size,
                              hipStream_t stream)
{
    const float* x   = (const float*)d_in[0];  // [B][P][D] float32
    const int*   dur = (const int*)d_in[1];    // [B][P] int32
    // d_in[2] = max_len scalar (2048), compile-time constant here.

    float* out = (float*)d_out;                          // [B][MAXLEN][D]
    float* mel = out + (size_t)LR_B * LR_MAXLEN * LR_D;  // [B] float-encoded

    lr_fused<<<LR_GBLOCKS, LR_THREADS, 0, stream>>>(
        dur, (const f32x4*)x, (f32x4*)out, mel);
}

// Round 7
// 23.030 us; speedup vs baseline: 1.0977x; 1.0160x over previous
//
#include <hip/hip_runtime.h>

// Problem constants (from setup_inputs): B=32, P=512, D=384, max_len=2048.
#define LR_B      32
#define LR_P      512
#define LR_D      384
#define LR_MAXLEN 2048
#define LR_V4     (LR_D / 4)        // 96 float4 per row
#define LR_FPB    32                // frames per block
#define LR_THREADS 256
#define LR_F4PB   (LR_FPB * LR_V4)  // 3072 float4 per block
#define LR_F4PT   (LR_F4PB / LR_THREADS)  // 12 float4 per thread

#define LR_CHUNKS  (LR_MAXLEN / LR_FPB)        // 64 chunks per batch
#define LR_GBLOCKS (LR_B * LR_CHUNKS)          // 2048 blocks (8 per CU)
#define LR_NXCD    8
#define LR_CPX     (LR_GBLOCKS / LR_NXCD)      // 256 blocks per XCD

typedef float f32x4 __attribute__((ext_vector_type(4)));

// ---------------------------------------------------------------------------
// Fully fused kernel, 256-thread blocks (8 blocks/CU vs R6's 4: same wave
// count, finer interleave so one block's scan prologue / load-wait epilogue
// hides under seven peers' store streams).
//   1. load the batch's 512 durations (2 per thread, int2),
//   2. wave-shuffle inclusive scan over pair-sums (no barriers in-wave),
//   3. scatter each thread's 2 phoneme intervals into the 32-entry window,
//   4. branchless 3-phase gather, regular write-back stores (R6 A/B: NT
//      stores de-rate the store pipe by ~8%).
// XCD-chunk swizzle: each XCD owns 4 consecutive batches (3.1 MB < 4 MB L2).
// ---------------------------------------------------------------------------
__global__ __launch_bounds__(LR_THREADS) void lr_fused(
    const int*   __restrict__ dur,     // [B][P]
    const f32x4* __restrict__ x4,      // [B][P][V4]
    f32x4*       __restrict__ out4,    // [B][MAXLEN][V4]
    float*       __restrict__ mel_out) // [B], float-encoded
{
    // Bijective chunked XCD swizzle (2048 % 8 == 0).
    const int bid = blockIdx.x;
    const int lb  = (bid & (LR_NXCD - 1)) * LR_CPX + (bid >> 3);

    const int b    = lb >> 6;           // lb / 64 : batch
    const int c    = lb & 63;           // chunk within batch
    const int base = c * LR_FPB;        // first frame of this block's window

    const int tid  = threadIdx.x;
    const int lane = tid & 63;
    const int wid  = tid >> 6;          // 4 waves

    __shared__ int smem_idx[LR_FPB];    // frame -> phoneme (-1 = masked)
    __shared__ int wsum[LR_THREADS / 64];

    if (tid < LR_FPB) smem_idx[tid] = -1;

    // Each thread owns phonemes 2*tid and 2*tid+1.
    const int2 d2 = ((const int2*)(dur + b * LR_P))[tid];
    const int  e0 = d2.x, e1 = d2.y;
    int s = e0 + e1;

    // Inclusive wave scan over pair-sums (6 shuffle steps, no barriers).
    #pragma unroll
    for (int off = 1; off < 64; off <<= 1) {
        int u = __shfl_up(s, off, 64);
        if (lane >= off) s += u;
    }
    if (lane == 63) wsum[wid] = s;
    __syncthreads();   // covers smem_idx init + wsum

    int woff = 0, total = 0;
    #pragma unroll
    for (int i = 0; i < LR_THREADS / 64; ++i) {
        int w = wsum[i];
        woff  += (i < wid) ? w : 0;
        total += w;
    }
    const int ends1  = s + woff;        // exclusive end of phoneme 2*tid+1
    const int ends0  = ends1 - e1;      // exclusive end of phoneme 2*tid
    const int start0 = ends0 - e0;      // start of phoneme 2*tid

    // Scatter this thread's two intervals into the block window (dur <= 4).
    {
        int lo = max(start0, base), hi = min(ends0, base + LR_FPB);
        for (int f = lo; f < hi; ++f) smem_idx[f - base] = 2 * tid;
        lo = max(ends0, base);  hi = min(ends1, base + LR_FPB);
        for (int f = lo; f < hi; ++f) smem_idx[f - base] = 2 * tid + 1;
    }
    if (c == 0 && tid == 0) mel_out[b] = (float)total;  // mel_len as float
    __syncthreads();

    // ---- 3-phase branchless gather --------------------------------------
    const f32x4* xb = x4 + (size_t)b * LR_P * LR_V4;
    f32x4*       ob = out4 + ((size_t)b * LR_MAXLEN + base) * LR_V4;

    int      pr[LR_F4PT];
    unsigned vv[LR_F4PT];
    #pragma unroll
    for (int k = 0; k < LR_F4PT; ++k) {
        const unsigned j     = tid + k * LR_THREADS;   // [0, 3072)
        const unsigned frame = j / LR_V4;              // magic-mul
        vv[k] = j - frame * LR_V4;
        pr[k] = smem_idx[frame];                       // broadcast read
    }

    f32x4 vals[LR_F4PT];
    #pragma unroll
    for (int k = 0; k < LR_F4PT; ++k) {
        const unsigned row = (unsigned)max(pr[k], 0);  // clamp: row 0 if masked
        vals[k] = xb[row * LR_V4 + vv[k]];             // unconditional -> MLP
    }

    const f32x4 zero = (f32x4){0.f, 0.f, 0.f, 0.f};
    #pragma unroll
    for (int k = 0; k < LR_F4PT; ++k) {
        f32x4 v = (pr[k] < 0) ? zero : vals[k];        // cndmask
        ob[tid + k * LR_THREADS] = v;                  // regular store
    }
}

extern "C" void kernel_launch(void* const* d_in, const int* in_sizes, int n_in,
                              void* d_out, int out_size, void* d_ws, size_t ws_size,
                              hipStream_t stream)
{
    const float* x   = (const float*)d_in[0];  // [B][P][D] float32
    const int*   dur = (const int*)d_in[1];    // [B][P] int32
    // d_in[2] = max_len scalar (2048), compile-time constant here.

    float* out = (float*)d_out;                          // [B][MAXLEN][D]
    float* mel = out + (size_t)LR_B * LR_MAXLEN * LR_D;  // [B] float-encoded

    lr_fused<<<LR_GBLOCKS, LR_THREADS, 0, stream>>>(
        dur, (const f32x4*)x, (f32x4*)out, mel);
}